// Round 3
// baseline (110.284 us; speedup 1.0000x reference)
//
#include <hip/hip_runtime.h>
#include <math.h>

#define BB 4
#define SS 2048
#define HH 256
#define NHH 8
#define EPSV 1e-5f
#define NC 8
#define CHW (SS/NC)     /* 256 cols per Psum chunk (attn_sums) */
#define NCO 4           /* O chunk-groups in attn_pv (balanced tile split) */
/* 1/sqrt(256) * log2(e): Q pre-scaled so exp(s/16) == exp2(QK^T) */
#define QPRE 0.09016844005556021f

#if __has_builtin(__builtin_amdgcn_exp2f)
#define EXP2F(x) __builtin_amdgcn_exp2f(x)
#else
#define EXP2F(x) __expf((x) * 0.6931471805599453f)
#endif

typedef unsigned short ushortT;
typedef __attribute__((ext_vector_type(8))) short bf16x8;
typedef __attribute__((ext_vector_type(4))) float f32x4;

__device__ inline ushortT f2bf(float f) {          // RNE
    union { float f; unsigned int u; } x; x.f = f;
    unsigned int r = x.u + 0x7FFFu + ((x.u >> 16) & 1u);
    return (ushortT)(r >> 16);
}
__device__ inline ushortT f2bf_rz(float f) {       // truncate (hot path)
    union { float f; unsigned int u; } x; x.f = f;
    return (ushortT)(x.u >> 16);
}
__device__ inline float bf2f(ushortT u) {
    union { unsigned int i; float f; } x; x.i = ((unsigned int)u) << 16;
    return x.f;
}

// ---------------- fused prep: x fp32->bf16 (+lengths out) and W->Wt bf16
__global__ __launch_bounds__(256) void prep(const float* __restrict__ x,
        ushortT* __restrict__ xb, const int* __restrict__ L,
        float* __restrict__ out_len,
        const float* __restrict__ Wa, const float* __restrict__ Wb,
        const float* __restrict__ Wc, const float* __restrict__ Wd,
        const float* __restrict__ We, ushortT* __restrict__ Wtb) {
    const int bid = blockIdx.x;
    if (bid < 1024) {
        const int i = (bid * 256 + threadIdx.x) << 3;
        float4 v0 = *(const float4*)(x + i);
        float4 v1 = *(const float4*)(x + i + 4);
        bf16x8 o;
        o[0] = (short)f2bf(v0.x); o[1] = (short)f2bf(v0.y);
        o[2] = (short)f2bf(v0.z); o[3] = (short)f2bf(v0.w);
        o[4] = (short)f2bf(v1.x); o[5] = (short)f2bf(v1.y);
        o[6] = (short)f2bf(v1.z); o[7] = (short)f2bf(v1.w);
        *(bf16x8*)(xb + i) = o;
        if (bid == 0 && threadIdx.x < BB) out_len[threadIdx.x] = (float)L[threadIdx.x];
        return;
    }
    const int wb = bid - 1024;                 // 0..319
    const int z = wb >> 6;                     // weight index
    const int rem = wb & 63;
    const int k0 = (rem >> 3) << 5, n0 = (rem & 7) << 5;
    const float* W = (z == 0) ? Wa : (z == 1) ? Wb : (z == 2) ? Wc : (z == 3) ? Wd : We;
    __shared__ float tile[32][33];
    const int t = threadIdx.x;
    const int r = t >> 3, c4 = (t & 7) << 2;
    float4 v = *(const float4*)(W + (size_t)(k0 + r) * HH + n0 + c4);
    tile[r][c4+0] = v.x; tile[r][c4+1] = v.y; tile[r][c4+2] = v.z; tile[r][c4+3] = v.w;
    __syncthreads();
    ushort4 o;
    o.x = f2bf(tile[c4+0][r]); o.y = f2bf(tile[c4+1][r]);
    o.z = f2bf(tile[c4+2][r]); o.w = f2bf(tile[c4+3][r]);
    *(ushort4*)(Wtb + (size_t)z * 65536 + (size_t)(n0 + r) * HH + k0 + c4) = o;
}

// ---------------- fused QKV MFMA GEMM; Q pre-scaled by QPRE; V stored transposed
__global__ __launch_bounds__(256) void gemm_qkv(const ushortT* __restrict__ A,
        const ushortT* __restrict__ Wtb,
        const float* __restrict__ bq, const float* __restrict__ bk,
        const float* __restrict__ bv,
        ushortT* __restrict__ Qb, ushortT* __restrict__ Kb,
        ushortT* __restrict__ Vt) {
    __shared__ ushortT As[64][264];
    __shared__ ushortT Ws[64][264];
    const int wsel = blockIdx.y >> 2;
    const int n0 = (blockIdx.y & 3) << 6;
    const ushortT* Wt = Wtb + (size_t)wsel * 65536;
    const float* bias = (wsel == 0) ? bq : (wsel == 1) ? bk : bv;
    const int tid = threadIdx.x;
    const int m0 = blockIdx.x << 6;
    #pragma unroll
    for (int t = 0; t < 8; ++t) {
        const int f = t * 256 + tid;
        const int r = f >> 5;
        const int cc = (f & 31) << 3;
        *(bf16x8*)&As[r][cc] = *(const bf16x8*)(A + (size_t)(m0 + r) * HH + cc);
        *(bf16x8*)&Ws[r][cc] = *(const bf16x8*)(Wt + (size_t)(n0 + r) * HH + cc);
    }
    __syncthreads();
    const int w = tid >> 6, lane = tid & 63;
    const int lg = lane >> 4, lc = lane & 15;
    const int wr = (w & 1) << 5, wc = (w >> 1) << 5;
    f32x4 acc[2][2];
    const f32x4 z4 = {0.f, 0.f, 0.f, 0.f};
    acc[0][0] = z4; acc[0][1] = z4; acc[1][0] = z4; acc[1][1] = z4;
    #pragma unroll
    for (int k0 = 0; k0 < 256; k0 += 32) {
        bf16x8 a0 = *(const bf16x8*)&As[wr + lc][k0 + lg*8];
        bf16x8 a1 = *(const bf16x8*)&As[wr + 16 + lc][k0 + lg*8];
        bf16x8 b0 = *(const bf16x8*)&Ws[wc + lc][k0 + lg*8];
        bf16x8 b1 = *(const bf16x8*)&Ws[wc + 16 + lc][k0 + lg*8];
        acc[0][0] = __builtin_amdgcn_mfma_f32_16x16x32_bf16(a0, b0, acc[0][0], 0, 0, 0);
        acc[0][1] = __builtin_amdgcn_mfma_f32_16x16x32_bf16(a0, b1, acc[0][1], 0, 0, 0);
        acc[1][0] = __builtin_amdgcn_mfma_f32_16x16x32_bf16(a1, b0, acc[1][0], 0, 0, 0);
        acc[1][1] = __builtin_amdgcn_mfma_f32_16x16x32_bf16(a1, b1, acc[1][1], 0, 0, 0);
    }
    ushortT* Out = (wsel == 0) ? Qb : Kb;
    #pragma unroll
    for (int RH = 0; RH < 2; ++RH)
        #pragma unroll
        for (int CH = 0; CH < 2; ++CH) {
            const int col = n0 + wc + CH*16 + lc;
            const float bvv = bias[col];
            float v[4];
            #pragma unroll
            for (int r = 0; r < 4; ++r) {
                v[r] = acc[RH][CH][r] + bvv;
                if (wsel == 0) v[r] *= QPRE;
            }
            if (wsel < 2) {
                #pragma unroll
                for (int r = 0; r < 4; ++r) {
                    const int row = m0 + wr + RH*16 + lg*4 + r;
                    Out[(size_t)row * HH + col] = f2bf(v[r]);
                }
            } else {
                const int row0 = m0 + wr + RH*16 + lg*4;
                const int bidx = row0 >> 11, s0 = row0 & (SS - 1);
                ushort4 o;
                o.x = f2bf(v[0]); o.y = f2bf(v[1]); o.z = f2bf(v[2]); o.w = f2bf(v[3]);
                *(ushort4*)(Vt + ((size_t)(bidx * HH + col)) * SS + s0) = o;
            }
        }
}

// ---------------- attention pass 1: partial exp2-sums per (chunk, head, row)
__global__ __launch_bounds__(512) void attn_sums(const ushortT* __restrict__ Qb,
        const ushortT* __restrict__ Kb, const int* __restrict__ lengths,
        float* __restrict__ Psum) {
    const int b = blockIdx.z, c = blockIdx.y;
    const int i0 = (63 - blockIdx.x) << 5;    // reversed: heavy tiles dispatch first
    const int len = lengths[b];
    const int jmax = min(i0 + 31, len - 1);
    const int jstart = c * CHW;
    if (i0 >= len || jstart > jmax) return;   // never read downstream
    const int tid = threadIdx.x;
    const int w = tid >> 6, lane = tid & 63;
    const int lg = lane >> 4, lc = lane & 15;
    bf16x8 qf[2];
    #pragma unroll
    for (int RH = 0; RH < 2; ++RH)
        qf[RH] = *(const bf16x8*)(Qb + ((size_t)(b * SS + i0 + RH*16 + lc)) * HH + w*32 + lg*8);
    const f32x4 z4 = {0.f, 0.f, 0.f, 0.f};
    float lsum[2][4] = {};
    const int jend = min(jstart + CHW - 32, (jmax >> 5) << 5);
    bf16x8 kf0 = *(const bf16x8*)(Kb + ((size_t)(b * SS + jstart + lc)) * HH + w*32 + lg*8);
    bf16x8 kf1 = *(const bf16x8*)(Kb + ((size_t)(b * SS + jstart + 16 + lc)) * HH + w*32 + lg*8);
    for (int j0 = jstart; j0 <= jend; j0 += 32) {
        bf16x8 ck0 = kf0, ck1 = kf1;
        if (j0 + 32 <= jend) {
            kf0 = *(const bf16x8*)(Kb + ((size_t)(b * SS + j0 + 32 + lc)) * HH + w*32 + lg*8);
            kf1 = *(const bf16x8*)(Kb + ((size_t)(b * SS + j0 + 48 + lc)) * HH + w*32 + lg*8);
        }
        f32x4 s[2][2];
        #pragma unroll
        for (int RH = 0; RH < 2; ++RH) {
            s[RH][0] = __builtin_amdgcn_mfma_f32_16x16x32_bf16(qf[RH], ck0, z4, 0, 0, 0);
            s[RH][1] = __builtin_amdgcn_mfma_f32_16x16x32_bf16(qf[RH], ck1, z4, 0, 0, 0);
        }
        if (j0 < i0) {          // full tile: no masks (invalid rows killed via inv=0)
            #pragma unroll
            for (int RH = 0; RH < 2; ++RH)
                #pragma unroll
                for (int r = 0; r < 4; ++r)
                    #pragma unroll
                    for (int CH = 0; CH < 2; ++CH)
                        lsum[RH][r] += EXP2F(s[RH][CH][r]);
        } else {                // diagonal tile: causal mask
            #pragma unroll
            for (int RH = 0; RH < 2; ++RH)
                #pragma unroll
                for (int r = 0; r < 4; ++r) {
                    const int row = i0 + RH*16 + lg*4 + r;
                    #pragma unroll
                    for (int CH = 0; CH < 2; ++CH) {
                        const int j = j0 + CH*16 + lc;
                        lsum[RH][r] += (j <= row) ? EXP2F(s[RH][CH][r]) : 0.f;
                    }
                }
        }
    }
    #pragma unroll
    for (int RH = 0; RH < 2; ++RH)
        #pragma unroll
        for (int r = 0; r < 4; ++r) {
            float v = lsum[RH][r];
            v += __shfl_xor(v, 1); v += __shfl_xor(v, 2);
            v += __shfl_xor(v, 4); v += __shfl_xor(v, 8);
            if (lc == 0)
                Psum[((size_t)(c * BB + b) * NHH + w) * SS + i0 + RH*16 + lg*4 + r] = v;
        }
}

// ---------------- attention pass 2: in-block inv + unnormalized P, mean, PV
// Active j-tiles [0,T) of each row-block are partitioned EQUALLY among NCO=4
// chunk-groups (remainder to low cgs -> contributing cgs are a prefix).
__global__ __launch_bounds__(512) void attn_pv(const ushortT* __restrict__ Qb,
        const ushortT* __restrict__ Kb, const ushortT* __restrict__ Vt,
        const int* __restrict__ lengths, const float* __restrict__ Psum,
        ushortT* __restrict__ OPart, float* __restrict__ out_mean) {
    __shared__ __align__(16) ushortT Pb[2][NHH][32][40];
    __shared__ float invS[NHH][32];
    const int b = blockIdx.z, cg = blockIdx.y;
    const int i0 = (63 - blockIdx.x) << 5;    // reversed: heavy tiles dispatch first
    const int len = lengths[b];
    const int tid = threadIdx.x;
    const int mr = tid >> 4, mc = (tid & 15) << 1;
    float* meanrow = out_mean + ((size_t)(b * SS + i0 + mr)) * SS + mc;
    // T = number of active 32-col tiles for this row-block (0 if rows invalid)
    const int T = (i0 < len) ? ((min(i0 + 31, len - 1) >> 5) + 1) : 0;
    // contiguous zero-fill of inactive cols [T*32, SS), quarter per cg, float4
    {
        const int zc0 = T << 5;
        const int zq = (SS - zc0) >> 2;           // multiple of 8
        const int c0 = zc0 + cg * zq;
        const int c1 = c0 + zq;
        float* mrow0 = out_mean + ((size_t)(b * SS + i0 + mr)) * SS;
        for (int cc2 = c0 + ((tid & 15) << 2); cc2 < c1; cc2 += 64)
            *(float4*)(mrow0 + cc2) = make_float4(0.f, 0.f, 0.f, 0.f);
    }
    // balanced prefix partition of [0,T): cg<r get q+1 tiles, others q
    const int q = T >> 2, r = T & (NCO - 1);
    const int t0 = cg * q + min(cg, r);
    const int t1 = t0 + q + (cg < r ? 1 : 0);
    if (t0 >= t1) return;
    // inverse denominators for this tile's 32 rows x 8 heads
    if (tid < NHH * 32) {
        const int hh = tid >> 5, row = i0 + (tid & 31);
        float rv = 0.f;
        if (row < len && hh < len) {
            float s = 0.f;
            const int ncv = (row >> 8) + 1;           // Psum chunks 0..row/CHW active
            for (int c2 = 0; c2 < ncv; ++c2)
                s += Psum[((size_t)(c2 * BB + b) * NHH + hh) * SS + row];
            rv = (s > 0.f) ? 1.0f / s : 0.f;
        }
        invS[hh][tid & 31] = rv;
    }
    __syncthreads();
    const int w = tid >> 6, lane = tid & 63;
    const int lg = lane >> 4, lc = lane & 15;
    bf16x8 qf[2];
    #pragma unroll
    for (int RH = 0; RH < 2; ++RH)
        qf[RH] = *(const bf16x8*)(Qb + ((size_t)(b * SS + i0 + RH*16 + lc)) * HH + w*32 + lg*8);
    float invv[2][4];
    #pragma unroll
    for (int RH = 0; RH < 2; ++RH)
        #pragma unroll
        for (int r2 = 0; r2 < 4; ++r2)
            invv[RH][r2] = invS[w][RH*16 + lg*4 + r2];
    // per-head inv (x 1/8) for this thread's mean row
    float invh8[NHH];
    #pragma unroll
    for (int hh = 0; hh < NHH; ++hh)
        invh8[hh] = invS[hh][mr] * 0.125f;
    const f32x4 z4 = {0.f, 0.f, 0.f, 0.f};
    f32x4 O[2][2];
    O[0][0] = z4; O[0][1] = z4; O[1][0] = z4; O[1][1] = z4;
    const int jstart = t0 << 5;
    bf16x8 kf0 = *(const bf16x8*)(Kb + ((size_t)(b * SS + jstart + lc)) * HH + w*32 + lg*8);
    bf16x8 kf1 = *(const bf16x8*)(Kb + ((size_t)(b * SS + jstart + 16 + lc)) * HH + w*32 + lg*8);
    bf16x8 vf0 = *(const bf16x8*)(Vt + ((size_t)(b * HH + w*32 + lc)) * SS + jstart + lg*8);
    bf16x8 vf1 = *(const bf16x8*)(Vt + ((size_t)(b * HH + w*32 + 16 + lc)) * SS + jstart + lg*8);
    int par = 0;
    for (int t = t0; t < t1; ++t) {
        const int j0 = t << 5;
        bf16x8 ck0 = kf0, ck1 = kf1, cv0 = vf0, cv1 = vf1;
        if (t + 1 < t1) {
            kf0 = *(const bf16x8*)(Kb + ((size_t)(b * SS + j0 + 32 + lc)) * HH + w*32 + lg*8);
            kf1 = *(const bf16x8*)(Kb + ((size_t)(b * SS + j0 + 48 + lc)) * HH + w*32 + lg*8);
            vf0 = *(const bf16x8*)(Vt + ((size_t)(b * HH + w*32 + lc)) * SS + j0 + 32 + lg*8);
            vf1 = *(const bf16x8*)(Vt + ((size_t)(b * HH + w*32 + 16 + lc)) * SS + j0 + 32 + lg*8);
        }
        f32x4 s[2][2];
        #pragma unroll
        for (int RH = 0; RH < 2; ++RH) {
            s[RH][0] = __builtin_amdgcn_mfma_f32_16x16x32_bf16(qf[RH], ck0, z4, 0, 0, 0);
            s[RH][1] = __builtin_amdgcn_mfma_f32_16x16x32_bf16(qf[RH], ck1, z4, 0, 0, 0);
        }
        if (j0 < i0) {      // full tile: unmasked, unnormalized
            #pragma unroll
            for (int RH = 0; RH < 2; ++RH)
                #pragma unroll
                for (int CH = 0; CH < 2; ++CH)
                    #pragma unroll
                    for (int r2 = 0; r2 < 4; ++r2)
                        Pb[par][w][RH*16 + lg*4 + r2][CH*16 + lc] =
                            f2bf_rz(EXP2F(s[RH][CH][r2]));
        } else {            // diagonal: causal mask
            #pragma unroll
            for (int RH = 0; RH < 2; ++RH)
                #pragma unroll
                for (int CH = 0; CH < 2; ++CH)
                    #pragma unroll
                    for (int r2 = 0; r2 < 4; ++r2) {
                        const int row = i0 + RH*16 + lg*4 + r2;
                        const int j = j0 + CH*16 + lc;
                        Pb[par][w][RH*16 + lg*4 + r2][CH*16 + lc] =
                            (j <= row) ? f2bf_rz(EXP2F(s[RH][CH][r2])) : (ushortT)0;
                    }
        }
        __syncthreads();
        #pragma unroll
        for (int RH = 0; RH < 2; ++RH) {
            bf16x8 pa = *(const bf16x8*)&Pb[par][w][RH*16 + lc][lg*8];
            O[RH][0] = __builtin_amdgcn_mfma_f32_16x16x32_bf16(pa, cv0, O[RH][0], 0, 0, 0);
            O[RH][1] = __builtin_amdgcn_mfma_f32_16x16x32_bf16(pa, cv1, O[RH][1], 0, 0, 0);
        }
        // atten_mean: sum_h e_h * inv_h / 8
        float m0 = 0.f, m1 = 0.f;
        #pragma unroll
        for (int ww = 0; ww < NHH; ++ww) {
            ushort2 t2 = *(const ushort2*)&Pb[par][ww][mr][mc];
            m0 += bf2f(t2.x) * invh8[ww]; m1 += bf2f(t2.y) * invh8[ww];
        }
        *(float2*)(meanrow + j0) = make_float2(m0, m1);
        par ^= 1;
    }
    // write partial O for this chunk-group (normalized; rows<len only ever read)
    ushortT* op = OPart + (size_t)cg * ((size_t)BB * SS * HH);
    #pragma unroll
    for (int RH = 0; RH < 2; ++RH)
        #pragma unroll
        for (int DH = 0; DH < 2; ++DH)
            #pragma unroll
            for (int r2 = 0; r2 < 4; ++r2)
                op[((size_t)(b * SS + i0 + RH*16 + lg*4 + r2)) * HH + w*32 + DH*16 + lc] =
                    f2bf(O[RH][DH][r2] * invv[RH][r2]);
}

// ---------------- residual add (x + sum of chunk-group partials) + LayerNorm
__global__ __launch_bounds__(256) void add_ln_attn(const float* __restrict__ x,
        const ushortT* __restrict__ OPart, const int* __restrict__ lengths,
        const float* __restrict__ g, const float* __restrict__ beta,
        float* __restrict__ out, ushortT* __restrict__ outb) {
    const int row = blockIdx.x;
    const int c = threadIdx.x;
    const int i = row & (SS - 1);
    const int len = lengths[row >> 11];
    const size_t base = (size_t)row * 256;
    float v = x[base + c];
    if (i < len) {
        const int ncv = min(NCO, (i >> 5) + 1);   // prefix cgs contributed
        for (int cc = 0; cc < ncv; ++cc)
            v += bf2f(OPart[(size_t)cc * ((size_t)BB * SS * HH) + base + c]);
    }
    __shared__ float red[8];
    float s = v;
    #pragma unroll
    for (int o = 32; o; o >>= 1) s += __shfl_down(s, o, 64);
    const int wid = c >> 6, lane = c & 63;
    if (lane == 0) red[wid] = s;
    __syncthreads();
    float mu = (red[0] + red[1] + red[2] + red[3]) * 0.00390625f;
    float d = v - mu;
    float q = d * d;
    #pragma unroll
    for (int o = 32; o; o >>= 1) q += __shfl_down(q, o, 64);
    if (lane == 0) red[4 + wid] = q;
    __syncthreads();
    float var = (red[4] + red[5] + red[6] + red[7]) * 0.00390625f;
    float res = d * rsqrtf(var + EPSV) * g[c] + beta[c];
    out[base + c] = res;
    outb[base + c] = f2bf(res);
}

// ---------------- fused FFN: F1 = gelu(X1Nb@W1+b1) in LDS; F2 = F1@W2+b2 in
// regs; then out = LayerNorm(X1N + F2). Block = 32-row strip x 256 cols.
__global__ __launch_bounds__(256) void ffn_fused(const ushortT* __restrict__ A,
        const float* __restrict__ X1N,
        const ushortT* __restrict__ W1t, const float* __restrict__ b1,
        const ushortT* __restrict__ W2t, const float* __restrict__ b2,
        const float* __restrict__ g2, const float* __restrict__ be2,
        float* __restrict__ out) {
    __shared__ ushortT Xs[32][264];
    __shared__ ushortT Ws[64][264];
    __shared__ ushortT F1s[32][264];
    __shared__ float redA[4][16];
    __shared__ float redB[4][16];
    const int tid = threadIdx.x;
    const int m0 = blockIdx.x << 5;
    // stage X strip (32x256 bf16)
    #pragma unroll
    for (int t = 0; t < 4; ++t) {
        const int f = t * 256 + tid;
        const int rr = f >> 5, cc = (f & 31) << 3;
        *(bf16x8*)&Xs[rr][cc] = *(const bf16x8*)(A + (size_t)(m0 + rr) * HH + cc);
    }
    const int w = tid >> 6, lane = tid & 63;
    const int lg = lane >> 4, lc = lane & 15;
    const int rw = (w & 1) << 4;              // 0/16: row half
    const int cw = (w >> 1) << 5;             // 0/32: col half within n-tile
    const f32x4 z4 = {0.f, 0.f, 0.f, 0.f};
    // -------- F1 phase: 4 n-tiles of 64 cols
    #pragma unroll
    for (int nt = 0; nt < 4; ++nt) {
        #pragma unroll
        for (int t = 0; t < 8; ++t) {
            const int f = t * 256 + tid;
            const int rr = f >> 5, cc = (f & 31) << 3;
            *(bf16x8*)&Ws[rr][cc] = *(const bf16x8*)(W1t + (size_t)(nt * 64 + rr) * HH + cc);
        }
        __syncthreads();
        f32x4 acc[2]; acc[0] = z4; acc[1] = z4;
        #pragma unroll
        for (int k0 = 0; k0 < 256; k0 += 32) {
            bf16x8 a  = *(const bf16x8*)&Xs[rw + lc][k0 + lg*8];
            bf16x8 b0 = *(const bf16x8*)&Ws[cw + lc][k0 + lg*8];
            bf16x8 b1v = *(const bf16x8*)&Ws[cw + 16 + lc][k0 + lg*8];
            acc[0] = __builtin_amdgcn_mfma_f32_16x16x32_bf16(a, b0, acc[0], 0, 0, 0);
            acc[1] = __builtin_amdgcn_mfma_f32_16x16x32_bf16(a, b1v, acc[1], 0, 0, 0);
        }
        #pragma unroll
        for (int CH = 0; CH < 2; ++CH) {
            const int col = nt * 64 + cw + CH * 16 + lc;
            const float bv = b1[col];
            #pragma unroll
            for (int r = 0; r < 4; ++r) {
                float v = acc[CH][r] + bv;
                v = 0.5f * v * (1.0f + erff(v * 0.70710678118f));
                F1s[rw + lg*4 + r][col] = f2bf(v);
            }
        }
        __syncthreads();
    }
    // -------- F2 phase: 4 n-tiles, accumulate in regs
    f32x4 f2acc[4][2];
    #pragma unroll
    for (int nt = 0; nt < 4; ++nt) {
        #pragma unroll
        for (int t = 0; t < 8; ++t) {
            const int f = t * 256 + tid;
            const int rr = f >> 5, cc = (f & 31) << 3;
            *(bf16x8*)&Ws[rr][cc] = *(const bf16x8*)(W2t + (size_t)(nt * 64 + rr) * HH + cc);
        }
        __syncthreads();
        f2acc[nt][0] = z4; f2acc[nt][1] = z4;
        #pragma unroll
        for (int k0 = 0; k0 < 256; k0 += 32) {
            bf16x8 a  = *(const bf16x8*)&F1s[rw + lc][k0 + lg*8];
            bf16x8 b0 = *(const bf16x8*)&Ws[cw + lc][k0 + lg*8];
            bf16x8 b1v = *(const bf16x8*)&Ws[cw + 16 + lc][k0 + lg*8];
            f2acc[nt][0] = __builtin_amdgcn_mfma_f32_16x16x32_bf16(a, b0, f2acc[nt][0], 0, 0, 0);
            f2acc[nt][1] = __builtin_amdgcn_mfma_f32_16x16x32_bf16(a, b1v, f2acc[nt][1], 0, 0, 0);
        }
        __syncthreads();
    }
    // -------- LN phase: v = X1N + F2 + b2; two-pass mean/var over 256 cols
    float v[4][2][4];
    float s[4] = {0.f, 0.f, 0.f, 0.f};
    #pragma unroll
    for (int nt = 0; nt < 4; ++nt)
        #pragma unroll
        for (int CH = 0; CH < 2; ++CH) {
            const int col = nt * 64 + cw + CH * 16 + lc;
            const float bv = b2[col];
            #pragma unroll
            for (int r = 0; r < 4; ++r) {
                const int row = m0 + rw + lg*4 + r;
                float vv = f2acc[nt][CH][r] + bv + X1N[(size_t)row * HH + col];
                v[nt][CH][r] = vv;
                s[r] += vv;
            }
        }
    #pragma unroll
    for (int r = 0; r < 4; ++r) {
        s[r] += __shfl_xor(s[r], 1); s[r] += __shfl_xor(s[r], 2);
        s[r] += __shfl_xor(s[r], 4); s[r] += __shfl_xor(s[r], 8);
    }
    if (lc == 0) {
        #pragma unroll
        for (int r = 0; r < 4; ++r) redA[w][lg*4 + r] = s[r];
    }
    __syncthreads();
    float mu[4];
    #pragma unroll
    for (int r = 0; r < 4; ++r)
        mu[r] = (redA[w][lg*4 + r] + redA[w ^ 2][lg*4 + r]) * 0.00390625f;
    float qs[4] = {0.f, 0.f, 0.f, 0.f};
    #pragma unroll
    for (int nt = 0; nt < 4; ++nt)
        #pragma unroll
        for (int CH = 0; CH < 2; ++CH)
            #pragma unroll
            for (int r = 0; r < 4; ++r) {
                const float d = v[nt][CH][r] - mu[r];
                qs[r] += d * d;
            }
    #pragma unroll
    for (int r = 0; r < 4; ++r) {
        qs[r] += __shfl_xor(qs[r], 1); qs[r] += __shfl_xor(qs[r], 2);
        qs[r] += __shfl_xor(qs[r], 4); qs[r] += __shfl_xor(qs[r], 8);
    }
    if (lc == 0) {
        #pragma unroll
        for (int r = 0; r < 4; ++r) redB[w][lg*4 + r] = qs[r];
    }
    __syncthreads();
    #pragma unroll
    for (int r = 0; r < 4; ++r) {
        const float var = (redB[w][lg*4 + r] + redB[w ^ 2][lg*4 + r]) * 0.00390625f;
        const float rs = rsqrtf(var + EPSV);
        const int row = m0 + rw + lg*4 + r;
        #pragma unroll
        for (int nt = 0; nt < 4; ++nt)
            #pragma unroll
            for (int CH = 0; CH < 2; ++CH) {
                const int col = nt * 64 + cw + CH * 16 + lc;
                out[(size_t)row * HH + col] =
                    (v[nt][CH][r] - mu[r]) * rs * g2[col] + be2[col];
            }
    }
}

extern "C" void kernel_launch(void* const* d_in, const int* in_sizes, int n_in,
                              void* d_out, int out_size, void* d_ws, size_t ws_size,
                              hipStream_t stream) {
    const float* x   = (const float*)d_in[0];
    const int* lengths = (const int*)d_in[1];
    const float* Wq  = (const float*)d_in[3];
    const float* bq  = (const float*)d_in[4];
    const float* Wk  = (const float*)d_in[5];
    const float* bk  = (const float*)d_in[6];
    const float* Wv  = (const float*)d_in[7];
    const float* bv  = (const float*)d_in[8];
    const float* W1  = (const float*)d_in[9];
    const float* b1  = (const float*)d_in[10];
    const float* W2  = (const float*)d_in[11];
    const float* b2  = (const float*)d_in[12];
    const float* g1  = (const float*)d_in[13];
    const float* be1 = (const float*)d_in[14];
    const float* g2  = (const float*)d_in[15];
    const float* be2 = (const float*)d_in[16];
    float* out = (float*)d_out;
    float* ws  = (float*)d_ws;

    const size_t NELT = (size_t)BB * SS * HH;     // 2,097,152
    const size_t M1 = 1024 * 1024;

    // ws layout (floats), phase-based reuse:
    // [0,1M)   xb (bf16) -> Psum (512K f32) -> X1Nb (bf16)
    // [1M,2M)  Qbf (bf16)
    // [2M,3M)  Kbf (bf16)
    // [3M,4M)  Vtb (bf16)
    // [4M,6M)  X1N (fp32)
    // [6M,6.16M) Wtb
    // [7M,11M) OPart: NCO chunk-groups x NELT bf16 (1M floats each)
    ushortT* xb  = (ushortT*)ws;
    float*   Psum = ws;
    ushortT* Qbf = (ushortT*)(ws + M1);
    ushortT* Kbf = (ushortT*)(ws + 2 * M1);
    ushortT* Vtb = (ushortT*)(ws + 3 * M1);
    float*   X1N  = ws + 4 * M1;
    ushortT* Wtb = (ushortT*)(ws + 6 * M1);
    ushortT* OPart = (ushortT*)(ws + 7 * M1);
    ushortT* X1Nb = (ushortT*)ws;

    float* out_y    = out;                        // [B,S,H]
    float* out_len  = out + NELT;                 // [B] as floats
    float* out_mean = out + NELT + 4;             // [B,S,S]

    prep<<<1344, 256, 0, stream>>>(x, xb, lengths, out_len, Wq, Wk, Wv, W1, W2, Wtb);
    gemm_qkv<<<dim3(128, 12), 256, 0, stream>>>(xb, Wtb, bq, bk, bv, Qbf, Kbf, Vtb);
    attn_sums<<<dim3(64, NC, 4), 512, 0, stream>>>(Qbf, Kbf, lengths, Psum);
    attn_pv<<<dim3(64, NCO, 4), 512, 0, stream>>>(Qbf, Kbf, Vtb, lengths, Psum, OPart, out_mean);
    add_ln_attn<<<8192, 256, 0, stream>>>(x, OPart, lengths, g1, be1, X1N, X1Nb);
    ffn_fused<<<256, 256, 0, stream>>>(X1Nb, X1N, Wtb + 3 * 65536, b1,
                                       Wtb + 4 * 65536, b2, g2, be2, out_y);
}

// Round 4
// 104.384 us; speedup vs baseline: 1.0565x; 1.0565x over previous
//
#include <hip/hip_runtime.h>
#include <math.h>

#define BB 4
#define SS 2048
#define HH 256
#define NHH 8
#define EPSV 1e-5f
#define NC 8
#define CHW (SS/NC)     /* 256 cols per Psum chunk (attn_sums) */
#define NCO 4           /* O chunk-groups in attn_pv (balanced tile split) */
/* 1/sqrt(256) * log2(e): Q pre-scaled so exp(s/16) == exp2(QK^T) */
#define QPRE 0.09016844005556021f

#if __has_builtin(__builtin_amdgcn_exp2f)
#define EXP2F(x) __builtin_amdgcn_exp2f(x)
#else
#define EXP2F(x) __expf((x) * 0.6931471805599453f)
#endif

typedef unsigned short ushortT;
typedef __attribute__((ext_vector_type(8))) short bf16x8;
typedef __attribute__((ext_vector_type(4))) float f32x4;

__device__ inline ushortT f2bf(float f) {          // RNE
    union { float f; unsigned int u; } x; x.f = f;
    unsigned int r = x.u + 0x7FFFu + ((x.u >> 16) & 1u);
    return (ushortT)(r >> 16);
}
__device__ inline ushortT f2bf_rz(float f) {       // truncate (hot path)
    union { float f; unsigned int u; } x; x.f = f;
    return (ushortT)(x.u >> 16);
}
__device__ inline float bf2f(ushortT u) {
    union { unsigned int i; float f; } x; x.i = ((unsigned int)u) << 16;
    return x.f;
}

// ---------------- fused prep: x fp32->bf16 (+lengths out) and W->Wt bf16
__global__ __launch_bounds__(256) void prep(const float* __restrict__ x,
        ushortT* __restrict__ xb, const int* __restrict__ L,
        float* __restrict__ out_len,
        const float* __restrict__ Wa, const float* __restrict__ Wb,
        const float* __restrict__ Wc, const float* __restrict__ Wd,
        const float* __restrict__ We, ushortT* __restrict__ Wtb) {
    const int bid = blockIdx.x;
    if (bid < 1024) {
        const int i = (bid * 256 + threadIdx.x) << 3;
        float4 v0 = *(const float4*)(x + i);
        float4 v1 = *(const float4*)(x + i + 4);
        bf16x8 o;
        o[0] = (short)f2bf(v0.x); o[1] = (short)f2bf(v0.y);
        o[2] = (short)f2bf(v0.z); o[3] = (short)f2bf(v0.w);
        o[4] = (short)f2bf(v1.x); o[5] = (short)f2bf(v1.y);
        o[6] = (short)f2bf(v1.z); o[7] = (short)f2bf(v1.w);
        *(bf16x8*)(xb + i) = o;
        if (bid == 0 && threadIdx.x < BB) out_len[threadIdx.x] = (float)L[threadIdx.x];
        return;
    }
    const int wb = bid - 1024;                 // 0..319
    const int z = wb >> 6;                     // weight index
    const int rem = wb & 63;
    const int k0 = (rem >> 3) << 5, n0 = (rem & 7) << 5;
    const float* W = (z == 0) ? Wa : (z == 1) ? Wb : (z == 2) ? Wc : (z == 3) ? Wd : We;
    __shared__ float tile[32][33];
    const int t = threadIdx.x;
    const int r = t >> 3, c4 = (t & 7) << 2;
    float4 v = *(const float4*)(W + (size_t)(k0 + r) * HH + n0 + c4);
    tile[r][c4+0] = v.x; tile[r][c4+1] = v.y; tile[r][c4+2] = v.z; tile[r][c4+3] = v.w;
    __syncthreads();
    ushort4 o;
    o.x = f2bf(tile[c4+0][r]); o.y = f2bf(tile[c4+1][r]);
    o.z = f2bf(tile[c4+2][r]); o.w = f2bf(tile[c4+3][r]);
    *(ushort4*)(Wtb + (size_t)z * 65536 + (size_t)(n0 + r) * HH + k0 + c4) = o;
}

// ---------------- fused QKV MFMA GEMM; Q pre-scaled by QPRE; V stored transposed
__global__ __launch_bounds__(256) void gemm_qkv(const ushortT* __restrict__ A,
        const ushortT* __restrict__ Wtb,
        const float* __restrict__ bq, const float* __restrict__ bk,
        const float* __restrict__ bv,
        ushortT* __restrict__ Qb, ushortT* __restrict__ Kb,
        ushortT* __restrict__ Vt) {
    __shared__ ushortT As[64][264];
    __shared__ ushortT Ws[64][264];
    const int wsel = blockIdx.y >> 2;
    const int n0 = (blockIdx.y & 3) << 6;
    const ushortT* Wt = Wtb + (size_t)wsel * 65536;
    const float* bias = (wsel == 0) ? bq : (wsel == 1) ? bk : bv;
    const int tid = threadIdx.x;
    const int m0 = blockIdx.x << 6;
    #pragma unroll
    for (int t = 0; t < 8; ++t) {
        const int f = t * 256 + tid;
        const int r = f >> 5;
        const int cc = (f & 31) << 3;
        *(bf16x8*)&As[r][cc] = *(const bf16x8*)(A + (size_t)(m0 + r) * HH + cc);
        *(bf16x8*)&Ws[r][cc] = *(const bf16x8*)(Wt + (size_t)(n0 + r) * HH + cc);
    }
    __syncthreads();
    const int w = tid >> 6, lane = tid & 63;
    const int lg = lane >> 4, lc = lane & 15;
    const int wr = (w & 1) << 5, wc = (w >> 1) << 5;
    f32x4 acc[2][2];
    const f32x4 z4 = {0.f, 0.f, 0.f, 0.f};
    acc[0][0] = z4; acc[0][1] = z4; acc[1][0] = z4; acc[1][1] = z4;
    #pragma unroll
    for (int k0 = 0; k0 < 256; k0 += 32) {
        bf16x8 a0 = *(const bf16x8*)&As[wr + lc][k0 + lg*8];
        bf16x8 a1 = *(const bf16x8*)&As[wr + 16 + lc][k0 + lg*8];
        bf16x8 b0 = *(const bf16x8*)&Ws[wc + lc][k0 + lg*8];
        bf16x8 b1 = *(const bf16x8*)&Ws[wc + 16 + lc][k0 + lg*8];
        acc[0][0] = __builtin_amdgcn_mfma_f32_16x16x32_bf16(a0, b0, acc[0][0], 0, 0, 0);
        acc[0][1] = __builtin_amdgcn_mfma_f32_16x16x32_bf16(a0, b1, acc[0][1], 0, 0, 0);
        acc[1][0] = __builtin_amdgcn_mfma_f32_16x16x32_bf16(a1, b0, acc[1][0], 0, 0, 0);
        acc[1][1] = __builtin_amdgcn_mfma_f32_16x16x32_bf16(a1, b1, acc[1][1], 0, 0, 0);
    }
    ushortT* Out = (wsel == 0) ? Qb : Kb;
    #pragma unroll
    for (int RH = 0; RH < 2; ++RH)
        #pragma unroll
        for (int CH = 0; CH < 2; ++CH) {
            const int col = n0 + wc + CH*16 + lc;
            const float bvv = bias[col];
            float v[4];
            #pragma unroll
            for (int r = 0; r < 4; ++r) {
                v[r] = acc[RH][CH][r] + bvv;
                if (wsel == 0) v[r] *= QPRE;
            }
            if (wsel < 2) {
                #pragma unroll
                for (int r = 0; r < 4; ++r) {
                    const int row = m0 + wr + RH*16 + lg*4 + r;
                    Out[(size_t)row * HH + col] = f2bf(v[r]);
                }
            } else {
                const int row0 = m0 + wr + RH*16 + lg*4;
                const int bidx = row0 >> 11, s0 = row0 & (SS - 1);
                ushort4 o;
                o.x = f2bf(v[0]); o.y = f2bf(v[1]); o.z = f2bf(v[2]); o.w = f2bf(v[3]);
                *(ushort4*)(Vt + ((size_t)(bidx * HH + col)) * SS + s0) = o;
            }
        }
}

// ---------------- MFMA GEMM for FFN: MODE 0 fp32 out; 2 bf16 out with GELU
template<int MODE>
__global__ __launch_bounds__(256) void gemm_mfma(const ushortT* __restrict__ A,
        const ushortT* __restrict__ Wt, const float* __restrict__ bias,
        void* __restrict__ Cv) {
    __shared__ ushortT As[64][264];
    __shared__ ushortT Ws[64][264];
    const int tid = threadIdx.x;
    const int m0 = blockIdx.x << 6;
    const int n0 = blockIdx.y << 6;
    #pragma unroll
    for (int t = 0; t < 8; ++t) {
        const int f = t * 256 + tid;
        const int r = f >> 5;
        const int cc = (f & 31) << 3;
        *(bf16x8*)&As[r][cc] = *(const bf16x8*)(A + (size_t)(m0 + r) * HH + cc);
        *(bf16x8*)&Ws[r][cc] = *(const bf16x8*)(Wt + (size_t)(n0 + r) * HH + cc);
    }
    __syncthreads();
    const int w = tid >> 6, lane = tid & 63;
    const int lg = lane >> 4, lc = lane & 15;
    const int wr = (w & 1) << 5, wc = (w >> 1) << 5;
    f32x4 acc[2][2];
    const f32x4 z4 = {0.f, 0.f, 0.f, 0.f};
    acc[0][0] = z4; acc[0][1] = z4; acc[1][0] = z4; acc[1][1] = z4;
    #pragma unroll
    for (int k0 = 0; k0 < 256; k0 += 32) {
        bf16x8 a0 = *(const bf16x8*)&As[wr + lc][k0 + lg*8];
        bf16x8 a1 = *(const bf16x8*)&As[wr + 16 + lc][k0 + lg*8];
        bf16x8 b0 = *(const bf16x8*)&Ws[wc + lc][k0 + lg*8];
        bf16x8 b1 = *(const bf16x8*)&Ws[wc + 16 + lc][k0 + lg*8];
        acc[0][0] = __builtin_amdgcn_mfma_f32_16x16x32_bf16(a0, b0, acc[0][0], 0, 0, 0);
        acc[0][1] = __builtin_amdgcn_mfma_f32_16x16x32_bf16(a0, b1, acc[0][1], 0, 0, 0);
        acc[1][0] = __builtin_amdgcn_mfma_f32_16x16x32_bf16(a1, b0, acc[1][0], 0, 0, 0);
        acc[1][1] = __builtin_amdgcn_mfma_f32_16x16x32_bf16(a1, b1, acc[1][1], 0, 0, 0);
    }
    #pragma unroll
    for (int RH = 0; RH < 2; ++RH)
        #pragma unroll
        for (int CH = 0; CH < 2; ++CH) {
            const int col = n0 + wc + CH*16 + lc;
            const float bv = bias[col];
            #pragma unroll
            for (int r = 0; r < 4; ++r) {
                const int row = m0 + wr + RH*16 + lg*4 + r;
                float v = acc[RH][CH][r] + bv;
                if (MODE == 2) v = 0.5f * v * (1.0f + erff(v * 0.70710678118f));
                if (MODE == 0) ((float*)Cv)[(size_t)row * HH + col] = v;
                else           ((ushortT*)Cv)[(size_t)row * HH + col] = f2bf(v);
            }
        }
}

// ---------------- attention pass 1: partial exp2-sums per (chunk, head, row)
__global__ __launch_bounds__(512) void attn_sums(const ushortT* __restrict__ Qb,
        const ushortT* __restrict__ Kb, const int* __restrict__ lengths,
        float* __restrict__ Psum) {
    const int b = blockIdx.z, c = blockIdx.y;
    const int i0 = (63 - blockIdx.x) << 5;    // reversed: heavy tiles dispatch first
    const int len = lengths[b];
    const int jmax = min(i0 + 31, len - 1);
    const int jstart = c * CHW;
    if (i0 >= len || jstart > jmax) return;   // never read downstream
    const int tid = threadIdx.x;
    const int w = tid >> 6, lane = tid & 63;
    const int lg = lane >> 4, lc = lane & 15;
    bf16x8 qf[2];
    #pragma unroll
    for (int RH = 0; RH < 2; ++RH)
        qf[RH] = *(const bf16x8*)(Qb + ((size_t)(b * SS + i0 + RH*16 + lc)) * HH + w*32 + lg*8);
    const f32x4 z4 = {0.f, 0.f, 0.f, 0.f};
    float lsum[2][4] = {};
    const int jend = min(jstart + CHW - 32, (jmax >> 5) << 5);
    bf16x8 kf0 = *(const bf16x8*)(Kb + ((size_t)(b * SS + jstart + lc)) * HH + w*32 + lg*8);
    bf16x8 kf1 = *(const bf16x8*)(Kb + ((size_t)(b * SS + jstart + 16 + lc)) * HH + w*32 + lg*8);
    for (int j0 = jstart; j0 <= jend; j0 += 32) {
        bf16x8 ck0 = kf0, ck1 = kf1;
        if (j0 + 32 <= jend) {
            kf0 = *(const bf16x8*)(Kb + ((size_t)(b * SS + j0 + 32 + lc)) * HH + w*32 + lg*8);
            kf1 = *(const bf16x8*)(Kb + ((size_t)(b * SS + j0 + 48 + lc)) * HH + w*32 + lg*8);
        }
        f32x4 s[2][2];
        #pragma unroll
        for (int RH = 0; RH < 2; ++RH) {
            s[RH][0] = __builtin_amdgcn_mfma_f32_16x16x32_bf16(qf[RH], ck0, z4, 0, 0, 0);
            s[RH][1] = __builtin_amdgcn_mfma_f32_16x16x32_bf16(qf[RH], ck1, z4, 0, 0, 0);
        }
        if (j0 < i0) {          // full tile: no masks (invalid rows killed via inv=0)
            #pragma unroll
            for (int RH = 0; RH < 2; ++RH)
                #pragma unroll
                for (int r = 0; r < 4; ++r)
                    #pragma unroll
                    for (int CH = 0; CH < 2; ++CH)
                        lsum[RH][r] += EXP2F(s[RH][CH][r]);
        } else {                // diagonal tile: causal mask
            #pragma unroll
            for (int RH = 0; RH < 2; ++RH)
                #pragma unroll
                for (int r = 0; r < 4; ++r) {
                    const int row = i0 + RH*16 + lg*4 + r;
                    #pragma unroll
                    for (int CH = 0; CH < 2; ++CH) {
                        const int j = j0 + CH*16 + lc;
                        lsum[RH][r] += (j <= row) ? EXP2F(s[RH][CH][r]) : 0.f;
                    }
                }
        }
    }
    #pragma unroll
    for (int RH = 0; RH < 2; ++RH)
        #pragma unroll
        for (int r = 0; r < 4; ++r) {
            float v = lsum[RH][r];
            v += __shfl_xor(v, 1); v += __shfl_xor(v, 2);
            v += __shfl_xor(v, 4); v += __shfl_xor(v, 8);
            if (lc == 0)
                Psum[((size_t)(c * BB + b) * NHH + w) * SS + i0 + RH*16 + lg*4 + r] = v;
        }
}

// ---------------- attention pass 2: in-block inv + unnormalized P, mean, PV
// Active j-tiles [0,T) of each row-block are partitioned EQUALLY among NCO=4
// chunk-groups (remainder to low cgs -> contributing cgs are a prefix).
// PV runs BEFORE the barrier (reads only own wave's Pb slice); only the
// cross-head mean reduction needs the barrier.
__global__ __launch_bounds__(512) void attn_pv(const ushortT* __restrict__ Qb,
        const ushortT* __restrict__ Kb, const ushortT* __restrict__ Vt,
        const int* __restrict__ lengths, const float* __restrict__ Psum,
        ushortT* __restrict__ OPart, float* __restrict__ out_mean) {
    __shared__ __align__(16) ushortT Pb[2][NHH][32][40];
    __shared__ float invS[NHH][32];
    const int b = blockIdx.z, cg = blockIdx.y;
    const int i0 = (63 - blockIdx.x) << 5;    // reversed: heavy tiles dispatch first
    const int len = lengths[b];
    const int tid = threadIdx.x;
    const int mr = tid >> 4, mc = (tid & 15) << 1;
    float* meanrow = out_mean + ((size_t)(b * SS + i0 + mr)) * SS + mc;
    // T = number of active 32-col tiles for this row-block (0 if rows invalid)
    const int T = (i0 < len) ? ((min(i0 + 31, len - 1) >> 5) + 1) : 0;
    // zero-fill mean for inactive tiles t in [T,64), strided across cgs
    for (int t = T + ((cg - T) & (NCO - 1)); t < 64; t += NCO)
        *(float2*)(meanrow + (t << 5)) = make_float2(0.f, 0.f);
    // balanced prefix partition of [0,T): cg<r get q+1 tiles, others q
    const int q = T >> 2, r = T & (NCO - 1);
    const int t0 = cg * q + min(cg, r);
    const int t1 = t0 + q + (cg < r ? 1 : 0);
    if (t0 >= t1) return;
    // inverse denominators for this tile's 32 rows x 8 heads
    if (tid < NHH * 32) {
        const int hh = tid >> 5, row = i0 + (tid & 31);
        float rv = 0.f;
        if (row < len && hh < len) {
            float s = 0.f;
            const int ncv = (row >> 8) + 1;           // Psum chunks 0..row/CHW active
            for (int c2 = 0; c2 < ncv; ++c2)
                s += Psum[((size_t)(c2 * BB + b) * NHH + hh) * SS + row];
            rv = (s > 0.f) ? 1.0f / s : 0.f;
        }
        invS[hh][tid & 31] = rv;
    }
    __syncthreads();
    const int w = tid >> 6, lane = tid & 63;
    const int lg = lane >> 4, lc = lane & 15;
    bf16x8 qf[2];
    #pragma unroll
    for (int RH = 0; RH < 2; ++RH)
        qf[RH] = *(const bf16x8*)(Qb + ((size_t)(b * SS + i0 + RH*16 + lc)) * HH + w*32 + lg*8);
    float invv[2][4];
    #pragma unroll
    for (int RH = 0; RH < 2; ++RH)
        #pragma unroll
        for (int r2 = 0; r2 < 4; ++r2)
            invv[RH][r2] = invS[w][RH*16 + lg*4 + r2];
    // per-head inv (x 1/8) for this thread's mean row
    float invh8[NHH];
    #pragma unroll
    for (int hh = 0; hh < NHH; ++hh)
        invh8[hh] = invS[hh][mr] * 0.125f;
    const f32x4 z4 = {0.f, 0.f, 0.f, 0.f};
    f32x4 O[2][2];
    O[0][0] = z4; O[0][1] = z4; O[1][0] = z4; O[1][1] = z4;
    const int jstart = t0 << 5;
    bf16x8 kf0 = *(const bf16x8*)(Kb + ((size_t)(b * SS + jstart + lc)) * HH + w*32 + lg*8);
    bf16x8 kf1 = *(const bf16x8*)(Kb + ((size_t)(b * SS + jstart + 16 + lc)) * HH + w*32 + lg*8);
    bf16x8 vf0 = *(const bf16x8*)(Vt + ((size_t)(b * HH + w*32 + lc)) * SS + jstart + lg*8);
    bf16x8 vf1 = *(const bf16x8*)(Vt + ((size_t)(b * HH + w*32 + 16 + lc)) * SS + jstart + lg*8);
    int par = 0;
    for (int t = t0; t < t1; ++t) {
        const int j0 = t << 5;
        bf16x8 ck0 = kf0, ck1 = kf1, cv0 = vf0, cv1 = vf1;
        if (t + 1 < t1) {
            kf0 = *(const bf16x8*)(Kb + ((size_t)(b * SS + j0 + 32 + lc)) * HH + w*32 + lg*8);
            kf1 = *(const bf16x8*)(Kb + ((size_t)(b * SS + j0 + 48 + lc)) * HH + w*32 + lg*8);
            vf0 = *(const bf16x8*)(Vt + ((size_t)(b * HH + w*32 + lc)) * SS + j0 + 32 + lg*8);
            vf1 = *(const bf16x8*)(Vt + ((size_t)(b * HH + w*32 + 16 + lc)) * SS + j0 + 32 + lg*8);
        }
        f32x4 s[2][2];
        #pragma unroll
        for (int RH = 0; RH < 2; ++RH) {
            s[RH][0] = __builtin_amdgcn_mfma_f32_16x16x32_bf16(qf[RH], ck0, z4, 0, 0, 0);
            s[RH][1] = __builtin_amdgcn_mfma_f32_16x16x32_bf16(qf[RH], ck1, z4, 0, 0, 0);
        }
        if (j0 < i0) {      // full tile: unmasked, unnormalized
            #pragma unroll
            for (int RH = 0; RH < 2; ++RH)
                #pragma unroll
                for (int CH = 0; CH < 2; ++CH)
                    #pragma unroll
                    for (int r2 = 0; r2 < 4; ++r2)
                        Pb[par][w][RH*16 + lg*4 + r2][CH*16 + lc] =
                            f2bf_rz(EXP2F(s[RH][CH][r2]));
        } else {            // diagonal: causal mask
            #pragma unroll
            for (int RH = 0; RH < 2; ++RH)
                #pragma unroll
                for (int CH = 0; CH < 2; ++CH)
                    #pragma unroll
                    for (int r2 = 0; r2 < 4; ++r2) {
                        const int row = i0 + RH*16 + lg*4 + r2;
                        const int j = j0 + CH*16 + lc;
                        Pb[par][w][RH*16 + lg*4 + r2][CH*16 + lc] =
                            (j <= row) ? f2bf_rz(EXP2F(s[RH][CH][r2])) : (ushortT)0;
                    }
        }
        // PV on own wave's Pb slice: wave-internal LDS ordering, no barrier
        #pragma unroll
        for (int RH = 0; RH < 2; ++RH) {
            bf16x8 pa = *(const bf16x8*)&Pb[par][w][RH*16 + lc][lg*8];
            O[RH][0] = __builtin_amdgcn_mfma_f32_16x16x32_bf16(pa, cv0, O[RH][0], 0, 0, 0);
            O[RH][1] = __builtin_amdgcn_mfma_f32_16x16x32_bf16(pa, cv1, O[RH][1], 0, 0, 0);
        }
        __syncthreads();
        // atten_mean: sum_h e_h * inv_h / 8 (reads all heads -> after barrier)
        float m0 = 0.f, m1 = 0.f;
        #pragma unroll
        for (int ww = 0; ww < NHH; ++ww) {
            ushort2 t2 = *(const ushort2*)&Pb[par][ww][mr][mc];
            m0 += bf2f(t2.x) * invh8[ww]; m1 += bf2f(t2.y) * invh8[ww];
        }
        *(float2*)(meanrow + j0) = make_float2(m0, m1);
        par ^= 1;
    }
    // write partial O for this chunk-group (normalized; rows<len only ever read)
    ushortT* op = OPart + (size_t)cg * ((size_t)BB * SS * HH);
    #pragma unroll
    for (int RH = 0; RH < 2; ++RH)
        #pragma unroll
        for (int DH = 0; DH < 2; ++DH)
            #pragma unroll
            for (int r2 = 0; r2 < 4; ++r2)
                op[((size_t)(b * SS + i0 + RH*16 + lg*4 + r2)) * HH + w*32 + DH*16 + lc] =
                    f2bf(O[RH][DH][r2] * invv[RH][r2]);
}

// ---------------- residual add (x + sum of chunk-group partials) + LayerNorm
__global__ __launch_bounds__(256) void add_ln_attn(const float* __restrict__ x,
        const ushortT* __restrict__ OPart, const int* __restrict__ lengths,
        const float* __restrict__ g, const float* __restrict__ beta,
        float* __restrict__ out, ushortT* __restrict__ outb) {
    const int row = blockIdx.x;
    const int c = threadIdx.x;
    const int i = row & (SS - 1);
    const int len = lengths[row >> 11];
    const size_t base = (size_t)row * 256;
    float v = x[base + c];
    if (i < len) {
        const int ncv = min(NCO, (i >> 5) + 1);   // prefix cgs contributed
        for (int cc = 0; cc < ncv; ++cc)
            v += bf2f(OPart[(size_t)cc * ((size_t)BB * SS * HH) + base + c]);
    }
    __shared__ float red[8];
    float s = v;
    #pragma unroll
    for (int o = 32; o; o >>= 1) s += __shfl_down(s, o, 64);
    const int wid = c >> 6, lane = c & 63;
    if (lane == 0) red[wid] = s;
    __syncthreads();
    float mu = (red[0] + red[1] + red[2] + red[3]) * 0.00390625f;
    float d = v - mu;
    float q = d * d;
    #pragma unroll
    for (int o = 32; o; o >>= 1) q += __shfl_down(q, o, 64);
    if (lane == 0) red[4 + wid] = q;
    __syncthreads();
    float var = (red[4] + red[5] + red[6] + red[7]) * 0.00390625f;
    float res = d * rsqrtf(var + EPSV) * g[c] + beta[c];
    out[base + c] = res;
    outb[base + c] = f2bf(res);
}

// ---------------- residual add + LayerNorm (final)
__global__ __launch_bounds__(256) void add_ln(const float* __restrict__ A,
        const float* __restrict__ Bv, const float* __restrict__ g,
        const float* __restrict__ beta, float* __restrict__ out) {
    const int row = blockIdx.x;
    const int c = threadIdx.x;
    const size_t base = (size_t)row * 256;
    float v = A[base + c] + Bv[base + c];
    __shared__ float red[8];
    float s = v;
    #pragma unroll
    for (int o = 32; o; o >>= 1) s += __shfl_down(s, o, 64);
    const int wid = c >> 6, lane = c & 63;
    if (lane == 0) red[wid] = s;
    __syncthreads();
    float mu = (red[0] + red[1] + red[2] + red[3]) * 0.00390625f;
    float d = v - mu;
    float q = d * d;
    #pragma unroll
    for (int o = 32; o; o >>= 1) q += __shfl_down(q, o, 64);
    if (lane == 0) red[4 + wid] = q;
    __syncthreads();
    float var = (red[4] + red[5] + red[6] + red[7]) * 0.00390625f;
    out[base + c] = d * rsqrtf(var + EPSV) * g[c] + beta[c];
}

extern "C" void kernel_launch(void* const* d_in, const int* in_sizes, int n_in,
                              void* d_out, int out_size, void* d_ws, size_t ws_size,
                              hipStream_t stream) {
    const float* x   = (const float*)d_in[0];
    const int* lengths = (const int*)d_in[1];
    const float* Wq  = (const float*)d_in[3];
    const float* bq  = (const float*)d_in[4];
    const float* Wk  = (const float*)d_in[5];
    const float* bk  = (const float*)d_in[6];
    const float* Wv  = (const float*)d_in[7];
    const float* bv  = (const float*)d_in[8];
    const float* W1  = (const float*)d_in[9];
    const float* b1  = (const float*)d_in[10];
    const float* W2  = (const float*)d_in[11];
    const float* b2  = (const float*)d_in[12];
    const float* g1  = (const float*)d_in[13];
    const float* be1 = (const float*)d_in[14];
    const float* g2  = (const float*)d_in[15];
    const float* be2 = (const float*)d_in[16];
    float* out = (float*)d_out;
    float* ws  = (float*)d_ws;

    const size_t NELT = (size_t)BB * SS * HH;     // 2,097,152
    const size_t M1 = 1024 * 1024;

    // ws layout (floats), phase-based reuse:
    // [0,1M)   xb (bf16) -> Psum (512K f32) -> X1Nb (bf16)
    // [1M,2M)  Qbf (bf16) -> F1b (bf16)
    // [2M,3M)  Kbf (bf16)
    // [3M,4M)  Vtb (bf16)
    // [4M,6M)  X1N (fp32)
    // [6M,6.16M) Wtb
    // [7M,11M) OPart: NCO chunk-groups x NELT bf16 (1M floats each)
    ushortT* xb  = (ushortT*)ws;
    float*   Psum = ws;
    ushortT* Qbf = (ushortT*)(ws + M1);
    ushortT* Kbf = (ushortT*)(ws + 2 * M1);
    ushortT* Vtb = (ushortT*)(ws + 3 * M1);
    float*   X1N  = ws + 4 * M1;
    ushortT* Wtb = (ushortT*)(ws + 6 * M1);
    ushortT* OPart = (ushortT*)(ws + 7 * M1);
    ushortT* X1Nb = (ushortT*)ws;
    ushortT* F1b  = (ushortT*)(ws + M1);
    float*   F2   = ws + 2 * M1;                  // Kbf/Vtb region, free by then

    float* out_y    = out;                        // [B,S,H]
    float* out_len  = out + NELT;                 // [B] as floats
    float* out_mean = out + NELT + 4;             // [B,S,S]

    prep<<<1344, 256, 0, stream>>>(x, xb, lengths, out_len, Wq, Wk, Wv, W1, W2, Wtb);
    gemm_qkv<<<dim3(128, 12), 256, 0, stream>>>(xb, Wtb, bq, bk, bv, Qbf, Kbf, Vtb);
    attn_sums<<<dim3(64, NC, 4), 512, 0, stream>>>(Qbf, Kbf, lengths, Psum);
    attn_pv<<<dim3(64, NCO, 4), 512, 0, stream>>>(Qbf, Kbf, Vtb, lengths, Psum, OPart, out_mean);
    add_ln_attn<<<8192, 256, 0, stream>>>(x, OPart, lengths, g1, be1, X1N, X1Nb);
    gemm_mfma<2><<<dim3(128, 4), 256, 0, stream>>>(X1Nb, Wtb + 3 * 65536, b1, (void*)F1b);
    gemm_mfma<0><<<dim3(128, 4), 256, 0, stream>>>(F1b,  Wtb + 4 * 65536, b2, (void*)F2);
    add_ln<<<8192, 256, 0, stream>>>(X1N, F2, g2, be2, out_y);
}